// Round 1
// baseline (422.645 us; speedup 1.0000x reference)
//
#include <hip/hip_runtime.h>
#include <math.h>

#define KS 7
#define PAD 3
#define NGRID 9801
#define NB 11            // blocks per dim (both scales)
#define NBLK (NB*NB)     // 121
#define BATCH 16
#define NFEAT 36

#define TX 32
#define TY 8

// ---------------- tables ----------------
__global__ void init_tables(float* __restrict__ rgam, float* __restrict__ convt,
                            float* __restrict__ meanf, float* __restrict__ w1d) {
    int i = blockIdx.x * blockDim.x + threadIdx.x;
    if (i < NGRID) {
        double a = (double)(float)(0.2 + 0.001 * (double)i);  // match float32 grid
        double g1 = lgamma(1.0 / a);
        double g2 = lgamma(2.0 / a);
        double g3 = lgamma(3.0 / a);
        rgam[i]  = (float)exp(2.0 * g2 - g1 - g3);
        convt[i] = (float)sqrt(exp(g1 - g3));
        meanf[i] = (float)exp(g2 - g1);
    }
    if (i == 0) {
        double g[7], s = 0.0;
        for (int k = 0; k < 7; ++k) { double d = (double)(k - 3); g[k] = exp(-d * d * 18.0 / 49.0); s += g[k]; }
        for (int k = 0; k < 7; ++k) w1d[k] = (float)(g[k] / s);
    }
}

// ---------------- MSCN normalize ----------------
__global__ void mscn_kernel(const float* __restrict__ img, float* __restrict__ out,
                            const float* __restrict__ w1d, int H, int W) {
    __shared__ float tile[TY + 6][TX + 6];
    __shared__ float w[7];
    int b = blockIdx.z;
    const float* im = img + (size_t)b * H * W;
    int ox0 = blockIdx.x * TX, oy0 = blockIdx.y * TY;
    int tid = threadIdx.y * TX + threadIdx.x;
    if (tid < 7) w[tid] = w1d[tid];
    for (int idx = tid; idx < (TY + 6) * (TX + 6); idx += TX * TY) {
        int ly = idx / (TX + 6), lx = idx % (TX + 6);
        int gy = min(max(oy0 + ly - PAD, 0), H - 1);
        int gx = min(max(ox0 + lx - PAD, 0), W - 1);
        tile[ly][lx] = im[(size_t)gy * W + gx];
    }
    __syncthreads();
    int ox = ox0 + threadIdx.x, oy = oy0 + threadIdx.y;
    if (ox < W && oy < H) {
        float mu = 0.f, m2 = 0.f;
        #pragma unroll
        for (int dy = 0; dy < 7; ++dy) {
            float wy = w[dy];
            #pragma unroll
            for (int dx = 0; dx < 7; ++dx) {
                float v = tile[threadIdx.y + dy][threadIdx.x + dx];
                float ww = wy * w[dx];
                mu += ww * v;
                m2 += ww * v * v;
            }
        }
        float sig = sqrtf(fabsf(m2 - mu * mu));
        float c = tile[threadIdx.y + PAD][threadIdx.x + PAD];
        out[(size_t)b * H * W + (size_t)oy * W + ox] = (c - mu) / (sig + 1.0f);
    }
}

// ---------------- 2x2 mean downsample ----------------
__global__ void downsample_kernel(const float* __restrict__ in, float* __restrict__ out,
                                  int Ho, int Wo, int B) {
    size_t idx = (size_t)blockIdx.x * blockDim.x + threadIdx.x;
    size_t total = (size_t)B * Ho * Wo;
    if (idx >= total) return;
    int x = (int)(idx % Wo); size_t t = idx / Wo;
    int y = (int)(t % Ho); int b = (int)(t / Ho);
    int Wi = Wo * 2;
    const float* p = in + ((size_t)b * (Ho * 2) + 2 * (size_t)y) * Wi + 2 * x;
    out[idx] = 0.25f * (p[0] + p[1] + p[Wi] + p[Wi + 1]);
}

// ---------------- per-block AGGD features ----------------
template <int K>
__global__ __launch_bounds__(256) void features_kernel(
        const float* __restrict__ norm,
        const float* __restrict__ rgam, const float* __restrict__ convt,
        const float* __restrict__ meanf,
        float* __restrict__ feats, int featOff) {
    __shared__ float blk[K][K];
    __shared__ float red[4][5][6];
    __shared__ float tot[5][6];
    __shared__ float sh_rhat[5], sh_lstd[5], sh_rstd[5];
    __shared__ float sdist[5][256];
    __shared__ int   sgidx[5][256];

    const int bIdx = blockIdx.x;        // 0..120
    const int b = blockIdx.y;           // batch
    const int bh = bIdx / NB, bw = bIdx % NB;
    const int W = K * NB;
    const float* base = norm + (size_t)b * W * W + (size_t)bh * K * W + (size_t)bw * K;
    const int tid = threadIdx.x;

    for (int idx = tid; idx < K * K; idx += 256) {
        int i = idx / K, j = idx % K;
        blk[i][j] = base[(size_t)i * W + j];
    }
    __syncthreads();

    float cl[5] = {0,0,0,0,0}, cr[5] = {0,0,0,0,0};
    float sl2[5] = {0,0,0,0,0}, sr2[5] = {0,0,0,0,0};
    float sab[5] = {0,0,0,0,0}, ssq[5] = {0,0,0,0,0};

    for (int idx = tid; idx < K * K; idx += 256) {
        int i = idx / K, j = idx % K;
        int im1 = i ? i - 1 : K - 1;
        int jm1 = j ? j - 1 : K - 1;
        int jp1 = (j == K - 1) ? 0 : j + 1;
        float v0 = blk[i][j];
        float vs[5];
        vs[0] = v0;
        vs[1] = v0 * blk[i][jm1];
        vs[2] = v0 * blk[im1][j];
        vs[3] = v0 * blk[im1][jm1];
        vs[4] = v0 * blk[im1][jp1];
        #pragma unroll
        for (int s = 0; s < 5; ++s) {
            float v = vs[s];
            float v2 = v * v;
            if (v < 0.f)      { cl[s] += 1.f; sl2[s] += v2; }
            else if (v > 0.f) { cr[s] += 1.f; sr2[s] += v2; }
            sab[s] += fabsf(v);
            ssq[s] += v2;
        }
    }
    // wave-64 shuffle reduce
    #pragma unroll
    for (int off = 32; off >= 1; off >>= 1) {
        #pragma unroll
        for (int s = 0; s < 5; ++s) {
            cl[s]  += __shfl_down(cl[s],  off);
            cr[s]  += __shfl_down(cr[s],  off);
            sl2[s] += __shfl_down(sl2[s], off);
            sr2[s] += __shfl_down(sr2[s], off);
            sab[s] += __shfl_down(sab[s], off);
            ssq[s] += __shfl_down(ssq[s], off);
        }
    }
    int wave = tid >> 6, lane = tid & 63;
    if (lane == 0) {
        #pragma unroll
        for (int s = 0; s < 5; ++s) {
            red[wave][s][0] = cl[s];  red[wave][s][1] = cr[s];
            red[wave][s][2] = sl2[s]; red[wave][s][3] = sr2[s];
            red[wave][s][4] = sab[s]; red[wave][s][5] = ssq[s];
        }
    }
    __syncthreads();
    if (tid < 30) {
        int s = tid / 6, q = tid % 6;
        tot[s][q] = red[0][s][q] + red[1][s][q] + red[2][s][q] + red[3][s][q];
    }
    __syncthreads();
    if (tid < 5) {
        int s = tid;
        float lstd = sqrtf(tot[s][2] / (tot[s][0] + 1e-8f));
        float rstd = sqrtf(tot[s][3] / (tot[s][1] + 1e-8f));
        float gh = lstd / rstd;
        const float n = (float)(K * K);
        float mab = tot[s][4] / n;
        float msq = tot[s][5] / n;
        float rhat = mab * mab / msq;
        float g2 = gh * gh;
        float rhatnorm = rhat * (gh * g2 + 1.f) * (gh + 1.f) / ((g2 + 1.f) * (g2 + 1.f));
        sh_rhat[s] = rhatnorm; sh_lstd[s] = lstd; sh_rstd[s] = rstd;
    }
    __syncthreads();

    // grid argmin (first-min tie-break)
    float bd[5] = {3.4e38f, 3.4e38f, 3.4e38f, 3.4e38f, 3.4e38f};
    int bg[5] = {0, 0, 0, 0, 0};
    for (int g = tid; g < NGRID; g += 256) {
        float r = rgam[g];
        #pragma unroll
        for (int s = 0; s < 5; ++s) {
            float d = fabsf(r - sh_rhat[s]);
            if (d < bd[s]) { bd[s] = d; bg[s] = g; }
        }
    }
    #pragma unroll
    for (int s = 0; s < 5; ++s) { sdist[s][tid] = bd[s]; sgidx[s][tid] = bg[s]; }
    __syncthreads();
    for (int stride = 128; stride >= 1; stride >>= 1) {
        if (tid < stride) {
            #pragma unroll
            for (int s = 0; s < 5; ++s) {
                float d2 = sdist[s][tid + stride]; int g2i = sgidx[s][tid + stride];
                float d1 = sdist[s][tid];          int g1i = sgidx[s][tid];
                if (d2 < d1 || (d2 == d1 && g2i < g1i)) { sdist[s][tid] = d2; sgidx[s][tid] = g2i; }
            }
        }
        __syncthreads();
    }

    if (tid < 5) {
        int s = tid;
        int gi = sgidx[s][0];
        float alpha = (float)(0.2 + 0.001 * (double)gi);
        float cv = convt[gi];
        float lb = sh_lstd[s] * cv, rb = sh_rstd[s] * cv;
        float* fo = feats + ((size_t)b * NBLK + bIdx) * NFEAT + featOff;
        if (s == 0) {
            fo[0] = alpha;
            fo[1] = 0.5f * (lb + rb);
        } else {
            int o = 2 + (s - 1) * 4;
            fo[o]     = alpha;
            fo[o + 1] = (rb - lb) * meanf[gi];
            fo[o + 2] = lb;
            fo[o + 3] = rb;
        }
    }
}

// ---------------- per-batch covariance + solve + score ----------------
__global__ __launch_bounds__(256) void score_kernel(
        const float* __restrict__ feats, const float* __restrict__ mu_pris,
        const float* __restrict__ cov_pris, float* __restrict__ out) {
    __shared__ float F[NBLK][NFEAT];
    __shared__ double mu[NFEAT];
    __shared__ double A[NFEAT][NFEAT + 1];
    __shared__ double fac[NFEAT];
    __shared__ int piv;
    int b = blockIdx.x, tid = threadIdx.x;
    const float* fp = feats + (size_t)b * NBLK * NFEAT;
    for (int i = tid; i < NBLK * NFEAT; i += 256) F[i / NFEAT][i % NFEAT] = fp[i];
    __syncthreads();
    if (tid < NFEAT) {
        double s = 0.0;
        for (int n = 0; n < NBLK; ++n) s += (double)F[n][tid];
        mu[tid] = s / (double)NBLK;
    }
    __syncthreads();
    for (int e = tid; e < NFEAT * NFEAT; e += 256) {
        int f = e / NFEAT, g = e % NFEAT;
        double mf = mu[f], mg = mu[g];
        double s = 0.0;
        for (int n = 0; n < NBLK; ++n) s += ((double)F[n][f] - mf) * ((double)F[n][g] - mg);
        A[f][g] = (s / (double)(NBLK - 1) + (double)cov_pris[f * NFEAT + g]) * 0.5;
    }
    if (tid < NFEAT) A[tid][NFEAT] = (double)mu_pris[tid] - mu[tid];
    __syncthreads();
    // Gaussian elimination with partial pivoting (cov is SPD -> pinv == inv)
    for (int k = 0; k < NFEAT; ++k) {
        if (tid == 0) {
            int p = k; double mx = fabs(A[k][k]);
            for (int r = k + 1; r < NFEAT; ++r) { double v = fabs(A[r][k]); if (v > mx) { mx = v; p = r; } }
            piv = p;
        }
        __syncthreads();
        int p = piv;
        if (p != k && tid <= NFEAT) { double t = A[k][tid]; A[k][tid] = A[p][tid]; A[p][tid] = t; }
        __syncthreads();
        if (tid > k && tid < NFEAT) fac[tid] = A[tid][k] / A[k][k];
        __syncthreads();
        for (int e = tid; e < NFEAT * (NFEAT + 1); e += 256) {
            int r = e / (NFEAT + 1), c = e % (NFEAT + 1);
            if (r > k && c >= k) A[r][c] -= fac[r] * A[k][c];
        }
        __syncthreads();
    }
    if (tid == 0) {
        double x[NFEAT];
        for (int i = NFEAT - 1; i >= 0; --i) {
            double s = A[i][NFEAT];
            for (int j = i + 1; j < NFEAT; ++j) s -= A[i][j] * x[j];
            x[i] = s / A[i][i];
        }
        double quad = 0.0;
        for (int i = 0; i < NFEAT; ++i) quad += ((double)mu_pris[i] - mu[i]) * x[i];
        out[b] = (float)sqrt(fmax(quad, 0.0));
    }
}

// ---------------- launch ----------------
extern "C" void kernel_launch(void* const* d_in, const int* in_sizes, int n_in,
                              void* d_out, int out_size, void* d_ws, size_t ws_size,
                              hipStream_t stream) {
    const float* img      = (const float*)d_in[0];
    const float* mu_pris  = (const float*)d_in[1];
    const float* cov_pris = (const float*)d_in[2];
    float* out = (float*)d_out;
    float* ws = (float*)d_ws;

    const int H1 = 1056, W1 = 1056, H2 = 528, W2 = 528;
    float* rgam  = ws;                 // 9801 (pad to 9856)
    float* convt = rgam + 9856;
    float* meanf = convt + 9856;
    float* w1d   = meanf + 9856;       // 8
    float* norm1 = w1d + 8;            // 16*1056*1056
    float* imgds = norm1 + (size_t)BATCH * H1 * W1;  // 16*528*528
    float* feats = imgds + (size_t)BATCH * H2 * W2;  // 16*121*36
    float* norm2 = norm1;              // alias: scale-1 features done before scale-2 mscn

    init_tables<<<(NGRID + 255) / 256, 256, 0, stream>>>(rgam, convt, meanf, w1d);

    dim3 mb(TX, TY);
    mscn_kernel<<<dim3((W1 + TX - 1) / TX, (H1 + TY - 1) / TY, BATCH), mb, 0, stream>>>(
        img, norm1, w1d, H1, W1);
    features_kernel<96><<<dim3(NBLK, BATCH), 256, 0, stream>>>(
        norm1, rgam, convt, meanf, feats, 0);

    downsample_kernel<<<(int)(((size_t)BATCH * H2 * W2 + 255) / 256), 256, 0, stream>>>(
        img, imgds, H2, W2, BATCH);
    mscn_kernel<<<dim3((W2 + TX - 1) / TX, (H2 + TY - 1) / TY, BATCH), mb, 0, stream>>>(
        imgds, norm2, w1d, H2, W2);
    features_kernel<48><<<dim3(NBLK, BATCH), 256, 0, stream>>>(
        norm2, rgam, convt, meanf, feats, 18);

    score_kernel<<<BATCH, 256, 0, stream>>>(feats, mu_pris, cov_pris, out);
}

// Round 2
// 266.126 us; speedup vs baseline: 1.5881x; 1.5881x over previous
//
#include <hip/hip_runtime.h>
#include <math.h>

#define NGRID 9801
#define NB 11            // blocks per dim (both scales)
#define NBLK (NB*NB)     // 121
#define BATCH 16
#define NFEAT 36

// ---------------- tables ----------------
__global__ void init_tables(float* __restrict__ rgam, float* __restrict__ convt,
                            float* __restrict__ meanf, float* __restrict__ w1d) {
    int i = blockIdx.x * blockDim.x + threadIdx.x;
    if (i < NGRID) {
        double a = (double)(float)(0.2 + 0.001 * (double)i);  // match float32 grid
        double g1 = lgamma(1.0 / a);
        double g2 = lgamma(2.0 / a);
        double g3 = lgamma(3.0 / a);
        rgam[i]  = (float)exp(2.0 * g2 - g1 - g3);
        convt[i] = (float)sqrt(exp(g1 - g3));
        meanf[i] = (float)exp(g2 - g1);
    }
    if (i == 0) {
        double g[7], s = 0.0;
        for (int k = 0; k < 7; ++k) { double d = (double)(k - 3); g[k] = exp(-d * d * 18.0 / 49.0); s += g[k]; }
        for (int k = 0; k < 7; ++k) w1d[k] = (float)(g[k] / s);
    }
}

// ---------------- separable sliding-window MSCN ----------------
// DS=1: img is (B,H,W), direct. DS=2: img is the ORIGINAL (B,2H,2W); we fuse
// the 2x2 mean downsample into the row loader. H,W are always OUTPUT dims.
// Each wave owns a 58-column slab (64 lanes, 3-lane halo each side), walks a
// row strip of height SH keeping 7-row filtered rings in registers.
__device__ __forceinline__ float bperm(int addr, float v) {
    return __int_as_float(__builtin_amdgcn_ds_bpermute(addr, __float_as_int(v)));
}

template <int DS>
__global__ __launch_bounds__(256) void mscn_sep(const float* __restrict__ img,
        float* __restrict__ out, const float* __restrict__ w1d,
        int H, int W, int SH) {
    const int tid = threadIdx.x;
    const int lane = tid & 63;
    const int basem3 = (lane - 3) << 2;   // bpermute byte addr of lane-3
    const int wv = tid >> 6;
    const int b = blockIdx.z;
    const int slab = blockIdx.x * 232 + wv * 58;
    const int gx = slab - 3 + lane;
    const int gxc = min(max(gx, 0), W - 1);
    const int y0 = blockIdx.y * SH;
    const int yend = min(y0 + SH, H);

    const float* im = nullptr;
    const float2* imp = nullptr;
    if constexpr (DS == 1) {
        im = img + (size_t)b * H * W + gxc;
    } else {
        imp = (const float2*)(img + (size_t)b * 4 * H * W) + gxc;
    }
    float* op = out + (size_t)b * H * W;
    const float w0=w1d[0], w1=w1d[1], w2=w1d[2], w3=w1d[3], w4=w1d[4], w5=w1d[5], w6=w1d[6];

    auto hrow = [&](int r, float& omu, float& om2) -> float {
        int rc = min(max(r, 0), H - 1);
        float v;
        if constexpr (DS == 1) {
            v = im[(size_t)rc * W];
        } else {
            float2 u = imp[(size_t)(2 * rc) * W];
            float2 l = imp[(size_t)(2 * rc) * W + W];
            v = (u.x + u.y + l.x + l.y) * 0.25f;
        }
        float a0 = bperm(basem3,      v);
        float a1 = bperm(basem3 + 4,  v);
        float a2 = bperm(basem3 + 8,  v);
        float a4 = bperm(basem3 + 16, v);
        float a5 = bperm(basem3 + 20, v);
        float a6 = bperm(basem3 + 24, v);
        omu = ((w0*a0 + w1*a1) + (w2*a2 + w3*v)) + ((w4*a4 + w5*a5) + w6*a6);
        om2 = ((w0*a0*a0 + w1*a1*a1) + (w2*a2*a2 + w3*v*v)) + ((w4*a4*a4 + w5*a5*a5) + w6*a6*a6);
        return v;
    };

    float m0,m1,mm2,m3,m4,m5,m6, q0,q1,q2,q3,q4,q5,q6;
    hrow(y0 - 3, m0, q0);
    hrow(y0 - 2, m1, q1);
    hrow(y0 - 1, mm2, q2);
    float rA = hrow(y0,     m3, q3);
    float rB = hrow(y0 + 1, m4, q4);
    float rC = hrow(y0 + 2, m5, q5);
    const bool doout = (lane >= 3) && (lane < 61) && (gx < W);

    #pragma unroll 7
    for (int y = y0; y < yend; ++y) {
        float rD = hrow(y + 3, m6, q6);
        float mu = ((w0*m0 + w1*m1) + (w2*mm2 + w3*m3)) + ((w4*m4 + w5*m5) + w6*m6);
        float s2 = ((w0*q0 + w1*q1) + (w2*q2 + w3*q3)) + ((w4*q4 + w5*q5) + w6*q6);
        float sig = __builtin_amdgcn_sqrtf(fabsf(s2 - mu * mu));
        if (doout) op[(size_t)y * W + gx] = (rA - mu) * __builtin_amdgcn_rcpf(sig + 1.0f);
        m0=m1; m1=mm2; mm2=m3; m3=m4; m4=m5; m5=m6;
        q0=q1; q1=q2; q2=q3; q3=q4; q4=q5; q5=q6;
        rA=rB; rB=rC; rC=rD;
    }
}

// ---------------- per-block AGGD features ----------------
template <int K>
__global__ __launch_bounds__(256) void features_kernel(
        const float* __restrict__ norm,
        const float* __restrict__ rgam, const float* __restrict__ convt,
        const float* __restrict__ meanf,
        float* __restrict__ feats, int featOff) {
    __shared__ float blk[K][K];
    __shared__ float red[4][5][6];
    __shared__ float tot[5][6];
    __shared__ float sh_rhat[5], sh_lstd[5], sh_rstd[5];
    __shared__ float sdist[5][256];
    __shared__ int   sgidx[5][256];

    const int bIdx = blockIdx.x;        // 0..120
    const int b = blockIdx.y;           // batch
    const int bh = bIdx / NB, bw = bIdx % NB;
    const int W = K * NB;
    const float* base = norm + (size_t)b * W * W + (size_t)bh * K * W + (size_t)bw * K;
    const int tid = threadIdx.x;

    for (int idx = tid; idx < K * K; idx += 256) {
        int i = idx / K, j = idx % K;
        blk[i][j] = base[(size_t)i * W + j];
    }
    __syncthreads();

    float cl[5] = {0,0,0,0,0}, cr[5] = {0,0,0,0,0};
    float sl2[5] = {0,0,0,0,0}, sr2[5] = {0,0,0,0,0};
    float sab[5] = {0,0,0,0,0}, ssq[5] = {0,0,0,0,0};

    for (int idx = tid; idx < K * K; idx += 256) {
        int i = idx / K, j = idx % K;
        int im1 = i ? i - 1 : K - 1;
        int jm1 = j ? j - 1 : K - 1;
        int jp1 = (j == K - 1) ? 0 : j + 1;
        float v0 = blk[i][j];
        float vs[5];
        vs[0] = v0;
        vs[1] = v0 * blk[i][jm1];
        vs[2] = v0 * blk[im1][j];
        vs[3] = v0 * blk[im1][jm1];
        vs[4] = v0 * blk[im1][jp1];
        #pragma unroll
        for (int s = 0; s < 5; ++s) {
            float v = vs[s];
            float v2 = v * v;
            if (v < 0.f)      { cl[s] += 1.f; sl2[s] += v2; }
            else if (v > 0.f) { cr[s] += 1.f; sr2[s] += v2; }
            sab[s] += fabsf(v);
            ssq[s] += v2;
        }
    }
    // wave-64 shuffle reduce
    #pragma unroll
    for (int off = 32; off >= 1; off >>= 1) {
        #pragma unroll
        for (int s = 0; s < 5; ++s) {
            cl[s]  += __shfl_down(cl[s],  off);
            cr[s]  += __shfl_down(cr[s],  off);
            sl2[s] += __shfl_down(sl2[s], off);
            sr2[s] += __shfl_down(sr2[s], off);
            sab[s] += __shfl_down(sab[s], off);
            ssq[s] += __shfl_down(ssq[s], off);
        }
    }
    int wave = tid >> 6, lane = tid & 63;
    if (lane == 0) {
        #pragma unroll
        for (int s = 0; s < 5; ++s) {
            red[wave][s][0] = cl[s];  red[wave][s][1] = cr[s];
            red[wave][s][2] = sl2[s]; red[wave][s][3] = sr2[s];
            red[wave][s][4] = sab[s]; red[wave][s][5] = ssq[s];
        }
    }
    __syncthreads();
    if (tid < 30) {
        int s = tid / 6, q = tid % 6;
        tot[s][q] = red[0][s][q] + red[1][s][q] + red[2][s][q] + red[3][s][q];
    }
    __syncthreads();
    if (tid < 5) {
        int s = tid;
        float lstd = sqrtf(tot[s][2] / (tot[s][0] + 1e-8f));
        float rstd = sqrtf(tot[s][3] / (tot[s][1] + 1e-8f));
        float gh = lstd / rstd;
        const float n = (float)(K * K);
        float mab = tot[s][4] / n;
        float msq = tot[s][5] / n;
        float rhat = mab * mab / msq;
        float g2 = gh * gh;
        float rhatnorm = rhat * (gh * g2 + 1.f) * (gh + 1.f) / ((g2 + 1.f) * (g2 + 1.f));
        sh_rhat[s] = rhatnorm; sh_lstd[s] = lstd; sh_rstd[s] = rstd;
    }
    __syncthreads();

    // grid argmin (first-min tie-break)
    float bd[5] = {3.4e38f, 3.4e38f, 3.4e38f, 3.4e38f, 3.4e38f};
    int bg[5] = {0, 0, 0, 0, 0};
    for (int g = tid; g < NGRID; g += 256) {
        float r = rgam[g];
        #pragma unroll
        for (int s = 0; s < 5; ++s) {
            float d = fabsf(r - sh_rhat[s]);
            if (d < bd[s]) { bd[s] = d; bg[s] = g; }
        }
    }
    #pragma unroll
    for (int s = 0; s < 5; ++s) { sdist[s][tid] = bd[s]; sgidx[s][tid] = bg[s]; }
    __syncthreads();
    for (int stride = 128; stride >= 1; stride >>= 1) {
        if (tid < stride) {
            #pragma unroll
            for (int s = 0; s < 5; ++s) {
                float d2 = sdist[s][tid + stride]; int g2i = sgidx[s][tid + stride];
                float d1 = sdist[s][tid];          int g1i = sgidx[s][tid];
                if (d2 < d1 || (d2 == d1 && g2i < g1i)) { sdist[s][tid] = d2; sgidx[s][tid] = g2i; }
            }
        }
        __syncthreads();
    }

    if (tid < 5) {
        int s = tid;
        int gi = sgidx[s][0];
        float alpha = (float)(0.2 + 0.001 * (double)gi);
        float cv = convt[gi];
        float lb = sh_lstd[s] * cv, rb = sh_rstd[s] * cv;
        float* fo = feats + ((size_t)b * NBLK + bIdx) * NFEAT + featOff;
        if (s == 0) {
            fo[0] = alpha;
            fo[1] = 0.5f * (lb + rb);
        } else {
            int o = 2 + (s - 1) * 4;
            fo[o]     = alpha;
            fo[o + 1] = (rb - lb) * meanf[gi];
            fo[o + 2] = lb;
            fo[o + 3] = rb;
        }
    }
}

// ---------------- per-batch covariance + solve + score ----------------
// cov = (cov_pris + cov_dist)/2 is SPD (lambda_min >= 0.25) -> no pivoting.
__global__ __launch_bounds__(256) void score_kernel(
        const float* __restrict__ feats, const float* __restrict__ mu_pris,
        const float* __restrict__ cov_pris, float* __restrict__ out) {
    __shared__ float F[NBLK][NFEAT];
    __shared__ double mu[NFEAT];
    __shared__ double A[NFEAT][NFEAT + 1];
    __shared__ double dff[NFEAT];
    __shared__ double fac[NFEAT];
    __shared__ double xs[NFEAT];
    int b = blockIdx.x, tid = threadIdx.x;
    const float* fp = feats + (size_t)b * NBLK * NFEAT;
    for (int i = tid; i < NBLK * NFEAT; i += 256) F[i / NFEAT][i % NFEAT] = fp[i];
    __syncthreads();
    if (tid < NFEAT) {
        double s = 0.0;
        for (int n = 0; n < NBLK; ++n) s += (double)F[n][tid];
        mu[tid] = s / (double)NBLK;
        dff[tid] = (double)mu_pris[tid] - mu[tid];
    }
    __syncthreads();
    for (int e = tid; e < NFEAT * NFEAT; e += 256) {
        int f = e / NFEAT, g = e % NFEAT;
        double mf = mu[f], mg = mu[g];
        double s = 0.0;
        for (int n = 0; n < NBLK; ++n) s += ((double)F[n][f] - mf) * ((double)F[n][g] - mg);
        A[f][g] = (s / (double)(NBLK - 1) + (double)cov_pris[f * NFEAT + g]) * 0.5;
    }
    if (tid < NFEAT) A[tid][NFEAT] = dff[tid];
    __syncthreads();
    // forward elimination, parallel rows (no pivot search)
    for (int k = 0; k < NFEAT - 1; ++k) {
        if (tid > k && tid < NFEAT) fac[tid] = A[tid][k] / A[k][k];
        __syncthreads();
        for (int e = tid; e < NFEAT * (NFEAT + 1); e += 256) {
            int r = e / (NFEAT + 1), c = e % (NFEAT + 1);
            if (r > k && c > k) A[r][c] -= fac[r] * A[k][c];
        }
        __syncthreads();
    }
    // back substitution, parallel column updates
    for (int i = NFEAT - 1; i >= 0; --i) {
        if (tid == i) xs[i] = A[i][NFEAT] / A[i][i];
        __syncthreads();
        if (tid < i) A[tid][NFEAT] -= A[tid][i] * xs[i];
        __syncthreads();
    }
    if (tid == 0) {
        double quad = 0.0;
        for (int i = 0; i < NFEAT; ++i) quad += dff[i] * xs[i];
        out[b] = (float)sqrt(fmax(quad, 0.0));
    }
}

// ---------------- launch ----------------
extern "C" void kernel_launch(void* const* d_in, const int* in_sizes, int n_in,
                              void* d_out, int out_size, void* d_ws, size_t ws_size,
                              hipStream_t stream) {
    const float* img      = (const float*)d_in[0];
    const float* mu_pris  = (const float*)d_in[1];
    const float* cov_pris = (const float*)d_in[2];
    float* out = (float*)d_out;
    float* ws = (float*)d_ws;

    const int H1 = 1056, W1 = 1056, H2 = 528, W2 = 528;
    float* rgam  = ws;                 // 9801 (pad to 9856)
    float* convt = rgam + 9856;
    float* meanf = convt + 9856;
    float* w1d   = meanf + 9856;       // 8
    float* norm1 = w1d + 8;            // 16*1056*1056
    float* feats = norm1 + (size_t)BATCH * H1 * W1;  // 16*121*36
    float* norm2 = norm1;              // alias: scale-1 features done before scale-2 mscn

    init_tables<<<(NGRID + 255) / 256, 256, 0, stream>>>(rgam, convt, meanf, w1d);

    // scale 1: W=1056 -> 5 x-tiles of 232 cols; 16 strips of 66 rows
    mscn_sep<1><<<dim3(5, 16, BATCH), 256, 0, stream>>>(img, norm1, w1d, H1, W1, 66);
    features_kernel<96><<<dim3(NBLK, BATCH), 256, 0, stream>>>(
        norm1, rgam, convt, meanf, feats, 0);

    // scale 2 (fused 2x2 downsample): W=528 -> 3 x-tiles; 16 strips of 33 rows
    mscn_sep<2><<<dim3(3, 16, BATCH), 256, 0, stream>>>(img, norm2, w1d, H2, W2, 33);
    features_kernel<48><<<dim3(NBLK, BATCH), 256, 0, stream>>>(
        norm2, rgam, convt, meanf, feats, 18);

    score_kernel<<<BATCH, 256, 0, stream>>>(feats, mu_pris, cov_pris, out);
}

// Round 3
// 205.277 us; speedup vs baseline: 2.0589x; 1.2964x over previous
//
#include <hip/hip_runtime.h>
#include <math.h>

#define NGRID 9801
#define NB 11            // blocks per dim (both scales)
#define NBLK (NB*NB)     // 121
#define BATCH 16
#define NFEAT 36

// ---------------- tables ----------------
__global__ void init_tables(float* __restrict__ rgam, float* __restrict__ convt,
                            float* __restrict__ meanf, float* __restrict__ w1d) {
    int i = blockIdx.x * blockDim.x + threadIdx.x;
    if (i < NGRID) {
        double a = (double)(float)(0.2 + 0.001 * (double)i);  // match float32 grid
        double g1 = lgamma(1.0 / a);
        double g2 = lgamma(2.0 / a);
        double g3 = lgamma(3.0 / a);
        rgam[i]  = (float)exp(2.0 * g2 - g1 - g3);
        convt[i] = (float)sqrt(exp(g1 - g3));
        meanf[i] = (float)exp(g2 - g1);
    }
    if (i == 0) {
        double g[7], s = 0.0;
        for (int k = 0; k < 7; ++k) { double d = (double)(k - 3); g[k] = exp(-d * d * 18.0 / 49.0); s += g[k]; }
        for (int k = 0; k < 7; ++k) w1d[k] = (float)(g[k] / s);
    }
}

// ---------------- separable sliding-window MSCN ----------------
__device__ __forceinline__ float bperm(int addr, float v) {
    return __int_as_float(__builtin_amdgcn_ds_bpermute(addr, __float_as_int(v)));
}

template <int DS>
__global__ __launch_bounds__(256) void mscn_sep(const float* __restrict__ img,
        float* __restrict__ out, const float* __restrict__ w1d,
        int H, int W, int SH) {
    const int tid = threadIdx.x;
    const int lane = tid & 63;
    const int basem3 = (lane - 3) << 2;   // bpermute byte addr of lane-3
    const int wv = tid >> 6;
    const int b = blockIdx.z;
    const int slab = blockIdx.x * 232 + wv * 58;
    const int gx = slab - 3 + lane;
    const int gxc = min(max(gx, 0), W - 1);
    const int y0 = blockIdx.y * SH;
    const int yend = min(y0 + SH, H);

    const float* im = nullptr;
    const float2* imp = nullptr;
    if constexpr (DS == 1) {
        im = img + (size_t)b * H * W + gxc;
    } else {
        imp = (const float2*)(img + (size_t)b * 4 * H * W) + gxc;
    }
    float* op = out + (size_t)b * H * W;
    const float w0=w1d[0], w1=w1d[1], w2=w1d[2], w3=w1d[3], w4=w1d[4], w5=w1d[5], w6=w1d[6];

    auto hrow = [&](int r, float& omu, float& om2) -> float {
        int rc = min(max(r, 0), H - 1);
        float v;
        if constexpr (DS == 1) {
            v = im[(size_t)rc * W];
        } else {
            float2 u = imp[(size_t)(2 * rc) * W];
            float2 l = imp[(size_t)(2 * rc) * W + W];
            v = (u.x + u.y + l.x + l.y) * 0.25f;
        }
        float a0 = bperm(basem3,      v);
        float a1 = bperm(basem3 + 4,  v);
        float a2 = bperm(basem3 + 8,  v);
        float a4 = bperm(basem3 + 16, v);
        float a5 = bperm(basem3 + 20, v);
        float a6 = bperm(basem3 + 24, v);
        omu = ((w0*a0 + w1*a1) + (w2*a2 + w3*v)) + ((w4*a4 + w5*a5) + w6*a6);
        om2 = ((w0*a0*a0 + w1*a1*a1) + (w2*a2*a2 + w3*v*v)) + ((w4*a4*a4 + w5*a5*a5) + w6*a6*a6);
        return v;
    };

    float m0,m1,mm2,m3,m4,m5,m6, q0,q1,q2,q3,q4,q5,q6;
    hrow(y0 - 3, m0, q0);
    hrow(y0 - 2, m1, q1);
    hrow(y0 - 1, mm2, q2);
    float rA = hrow(y0,     m3, q3);
    float rB = hrow(y0 + 1, m4, q4);
    float rC = hrow(y0 + 2, m5, q5);
    const bool doout = (lane >= 3) && (lane < 61) && (gx < W);

    #pragma unroll 7
    for (int y = y0; y < yend; ++y) {
        float rD = hrow(y + 3, m6, q6);
        float mu = ((w0*m0 + w1*m1) + (w2*mm2 + w3*m3)) + ((w4*m4 + w5*m5) + w6*m6);
        float s2 = ((w0*q0 + w1*q1) + (w2*q2 + w3*q3)) + ((w4*q4 + w5*q5) + w6*q6);
        float sig = __builtin_amdgcn_sqrtf(fabsf(s2 - mu * mu));
        if (doout) op[(size_t)y * W + gx] = (rA - mu) * __builtin_amdgcn_rcpf(sig + 1.0f);
        m0=m1; m1=mm2; mm2=m3; m3=m4; m4=m5; m5=m6;
        q0=q1; q1=q2; q2=q3; q3=q4; q4=q5; q5=q6;
        rA=rB; rB=rC; rC=rD;
    }
}

// ---------------- per-block statistics (no argmin) ----------------
// Writes 25 floats per (batch, block): [signal][cl, cr, sl2, sr2, sab]
template <int K>
__global__ __launch_bounds__(256) void stats_kernel(
        const float* __restrict__ norm, float* __restrict__ stats) {
    __shared__ float blk[K][K];
    __shared__ float red[4][25];

    const int bIdx = blockIdx.x;        // 0..120
    const int b = blockIdx.y;           // batch
    const int bh = bIdx / NB, bw = bIdx % NB;
    const int W = K * NB;
    const float* base = norm + (size_t)b * W * W + (size_t)bh * K * W + (size_t)bw * K;
    const int tid = threadIdx.x;

    for (int idx = tid; idx < K * K; idx += 256) {
        blk[idx / K][idx % K] = base[(size_t)(idx / K) * W + (idx % K)];
    }
    __syncthreads();

    float acc[5][5];
    #pragma unroll
    for (int s = 0; s < 5; ++s)
        #pragma unroll
        for (int q = 0; q < 5; ++q) acc[s][q] = 0.f;

    for (int idx = tid; idx < K * K; idx += 256) {
        int i = idx / K, j = idx % K;
        int im1 = i ? i - 1 : K - 1;
        int jm1 = j ? j - 1 : K - 1;
        int jp1 = (j == K - 1) ? 0 : j + 1;
        float v0 = blk[i][j];
        float vs[5];
        vs[0] = v0;
        vs[1] = v0 * blk[i][jm1];
        vs[2] = v0 * blk[im1][j];
        vs[3] = v0 * blk[im1][jm1];
        vs[4] = v0 * blk[im1][jp1];
        #pragma unroll
        for (int s = 0; s < 5; ++s) {
            float v = vs[s];
            float v2 = v * v;
            if (v < 0.f)      { acc[s][0] += 1.f; acc[s][2] += v2; }
            else if (v > 0.f) { acc[s][1] += 1.f; acc[s][3] += v2; }
            acc[s][4] += fabsf(v);
        }
    }
    // wave-64 shuffle reduce (25 values)
    #pragma unroll
    for (int off = 32; off >= 1; off >>= 1)
        #pragma unroll
        for (int s = 0; s < 5; ++s)
            #pragma unroll
            for (int q = 0; q < 5; ++q)
                acc[s][q] += __shfl_down(acc[s][q], off);

    int wave = tid >> 6, lane = tid & 63;
    if (lane == 0) {
        #pragma unroll
        for (int s = 0; s < 5; ++s)
            #pragma unroll
            for (int q = 0; q < 5; ++q) red[wave][s * 5 + q] = acc[s][q];
    }
    __syncthreads();
    if (tid < 25) {
        stats[((size_t)b * NBLK + bIdx) * 25 + tid] =
            red[0][tid] + red[1][tid] + red[2][tid] + red[3][tid];
    }
}

// ---------------- AGGD closed-form + binary-search argmin ----------------
// One thread per (scale, batch, block, signal): 2*16*121*5 = 19360 threads.
__global__ __launch_bounds__(256) void aggd_kernel(
        const float* __restrict__ stats1, const float* __restrict__ stats2,
        const float* __restrict__ rgam, const float* __restrict__ convt,
        const float* __restrict__ meanf, float* __restrict__ feats) {
    __shared__ float rg[NGRID];
    for (int i = threadIdx.x; i < NGRID; i += 256) rg[i] = rgam[i];
    __syncthreads();

    int gid = blockIdx.x * 256 + threadIdx.x;
    if (gid >= 2 * BATCH * NBLK * 5) return;
    int s = gid % 5; int t = gid / 5;
    int blk = t % NBLK; t /= NBLK;
    int b = t % BATCH; int scale = t / BATCH;

    const float* st = (scale ? stats2 : stats1) + ((size_t)b * NBLK + blk) * 25 + s * 5;
    float cl = st[0], cr = st[1], sl2 = st[2], sr2 = st[3], sab = st[4];
    float n = scale ? (48.f * 48.f) : (96.f * 96.f);

    float lstd = sqrtf(sl2 / (cl + 1e-8f));
    float rstd = sqrtf(sr2 / (cr + 1e-8f));
    float gh = lstd / rstd;
    float mab = sab / n;
    float msq = (sl2 + sr2) / n;
    float rhat = mab * mab / msq;
    float g2 = gh * gh;
    float x = rhat * (gh * g2 + 1.f) * (gh + 1.f) / ((g2 + 1.f) * (g2 + 1.f));

    // lower_bound: first index with rg[i] >= x  (rg monotone increasing)
    int lo = 0, hi = NGRID;
    while (lo < hi) {
        int mid = (lo + hi) >> 1;
        if (rg[mid] < x) lo = mid + 1; else hi = mid;
    }
    int gi;
    if (lo <= 0) gi = 0;
    else if (lo >= NGRID) gi = NGRID - 1;
    else {
        float dlo = x - rg[lo - 1];   // > 0
        float dhi = rg[lo] - x;       // >= 0
        gi = (dlo <= dhi) ? lo - 1 : lo;   // tie -> lower index (first-min)
    }

    float alpha = (float)(0.2 + 0.001 * (double)gi);
    float cv = convt[gi];
    float lb = lstd * cv, rb = rstd * cv;
    float* fo = feats + ((size_t)b * NBLK + blk) * NFEAT + (scale ? 18 : 0);
    if (s == 0) {
        fo[0] = alpha;
        fo[1] = 0.5f * (lb + rb);
    } else {
        int o = 2 + (s - 1) * 4;
        fo[o]     = alpha;
        fo[o + 1] = (rb - lb) * meanf[gi];
        fo[o + 2] = lb;
        fo[o + 3] = rb;
    }
}

// ---------------- per-batch covariance + solve + score ----------------
// cov = (cov_pris + cov_dist)/2 is SPD (lambda_min >= 0.25) -> no pivoting.
__global__ __launch_bounds__(256) void score_kernel(
        const float* __restrict__ feats, const float* __restrict__ mu_pris,
        const float* __restrict__ cov_pris, float* __restrict__ out) {
    __shared__ float F[NBLK][NFEAT];
    __shared__ double mu[NFEAT];
    __shared__ double A[NFEAT][NFEAT + 1];
    __shared__ double dff[NFEAT];
    __shared__ double fac[NFEAT];
    __shared__ double xs[NFEAT];
    int b = blockIdx.x, tid = threadIdx.x;
    const float* fp = feats + (size_t)b * NBLK * NFEAT;
    for (int i = tid; i < NBLK * NFEAT; i += 256) F[i / NFEAT][i % NFEAT] = fp[i];
    __syncthreads();
    if (tid < NFEAT) {
        double s = 0.0;
        for (int n = 0; n < NBLK; ++n) s += (double)F[n][tid];
        mu[tid] = s / (double)NBLK;
        dff[tid] = (double)mu_pris[tid] - mu[tid];
    }
    __syncthreads();
    for (int e = tid; e < NFEAT * NFEAT; e += 256) {
        int f = e / NFEAT, g = e % NFEAT;
        double mf = mu[f], mg = mu[g];
        double s = 0.0;
        for (int n = 0; n < NBLK; ++n) s += ((double)F[n][f] - mf) * ((double)F[n][g] - mg);
        A[f][g] = (s / (double)(NBLK - 1) + (double)cov_pris[f * NFEAT + g]) * 0.5;
    }
    if (tid < NFEAT) A[tid][NFEAT] = dff[tid];
    __syncthreads();
    // forward elimination, parallel rows (no pivot search)
    for (int k = 0; k < NFEAT - 1; ++k) {
        if (tid > k && tid < NFEAT) fac[tid] = A[tid][k] / A[k][k];
        __syncthreads();
        for (int e = tid; e < NFEAT * (NFEAT + 1); e += 256) {
            int r = e / (NFEAT + 1), c = e % (NFEAT + 1);
            if (r > k && c > k) A[r][c] -= fac[r] * A[k][c];
        }
        __syncthreads();
    }
    // back substitution, parallel column updates
    for (int i = NFEAT - 1; i >= 0; --i) {
        if (tid == i) xs[i] = A[i][NFEAT] / A[i][i];
        __syncthreads();
        if (tid < i) A[tid][NFEAT] -= A[tid][i] * xs[i];
        __syncthreads();
    }
    if (tid == 0) {
        double quad = 0.0;
        for (int i = 0; i < NFEAT; ++i) quad += dff[i] * xs[i];
        out[b] = (float)sqrt(fmax(quad, 0.0));
    }
}

// ---------------- launch ----------------
extern "C" void kernel_launch(void* const* d_in, const int* in_sizes, int n_in,
                              void* d_out, int out_size, void* d_ws, size_t ws_size,
                              hipStream_t stream) {
    const float* img      = (const float*)d_in[0];
    const float* mu_pris  = (const float*)d_in[1];
    const float* cov_pris = (const float*)d_in[2];
    float* out = (float*)d_out;
    float* ws = (float*)d_ws;

    const int H1 = 1056, W1 = 1056, H2 = 528, W2 = 528;
    float* rgam  = ws;                 // 9801 (pad to 9856)
    float* convt = rgam + 9856;
    float* meanf = convt + 9856;
    float* w1d   = meanf + 9856;       // 8
    float* norm1 = w1d + 8;            // 16*1056*1056
    float* stats1 = norm1 + (size_t)BATCH * H1 * W1;   // 16*121*25
    float* stats2 = stats1 + BATCH * NBLK * 25;
    float* feats  = stats2 + BATCH * NBLK * 25;        // 16*121*36
    float* norm2 = norm1;              // alias: scale-1 stats done before scale-2 mscn

    init_tables<<<(NGRID + 255) / 256, 256, 0, stream>>>(rgam, convt, meanf, w1d);

    // scale 1: W=1056 -> 5 x-tiles of 232 cols; 16 strips of 66 rows
    mscn_sep<1><<<dim3(5, 16, BATCH), 256, 0, stream>>>(img, norm1, w1d, H1, W1, 66);
    stats_kernel<96><<<dim3(NBLK, BATCH), 256, 0, stream>>>(norm1, stats1);

    // scale 2 (fused 2x2 downsample): W=528 -> 3 x-tiles; 16 strips of 33 rows
    mscn_sep<2><<<dim3(3, 16, BATCH), 256, 0, stream>>>(img, norm2, w1d, H2, W2, 33);
    stats_kernel<48><<<dim3(NBLK, BATCH), 256, 0, stream>>>(norm2, stats2);

    aggd_kernel<<<(2 * BATCH * NBLK * 5 + 255) / 256, 256, 0, stream>>>(
        stats1, stats2, rgam, convt, meanf, feats);

    score_kernel<<<BATCH, 256, 0, stream>>>(feats, mu_pris, cov_pris, out);
}

// Round 4
// 191.032 us; speedup vs baseline: 2.2124x; 1.0746x over previous
//
#include <hip/hip_runtime.h>
#include <math.h>

#define NGRID 9801
#define NB 11            // blocks per dim (both scales)
#define NBLK (NB*NB)     // 121
#define BATCH 16
#define NFEAT 36

// ---------------- tables ----------------
__global__ void init_tables(float* __restrict__ rgam, float* __restrict__ convt,
                            float* __restrict__ meanf, float* __restrict__ w1d) {
    int i = blockIdx.x * blockDim.x + threadIdx.x;
    if (i < NGRID) {
        double a = (double)(float)(0.2 + 0.001 * (double)i);  // match float32 grid
        double g1 = lgamma(1.0 / a);
        double g2 = lgamma(2.0 / a);
        double g3 = lgamma(3.0 / a);
        rgam[i]  = (float)exp(2.0 * g2 - g1 - g3);
        convt[i] = (float)sqrt(exp(g1 - g3));
        meanf[i] = (float)exp(g2 - g1);
    }
    if (i == 0) {
        double g[7], s = 0.0;
        for (int k = 0; k < 7; ++k) { double d = (double)(k - 3); g[k] = exp(-d * d * 18.0 / 49.0); s += g[k]; }
        for (int k = 0; k < 7; ++k) w1d[k] = (float)(g[k] / s);
    }
}

__device__ __forceinline__ float bperm(int addr, float v) {
    return __int_as_float(__builtin_amdgcn_ds_bpermute(addr, __float_as_int(v)));
}

// ---------------- fused MSCN + per-block stats ----------------
// One WG per (NIQE block, batch). 4 waves, each owning a 48-col slab strip:
//   K=96: 2 slabs x 2 strips of 48 rows;  K=48: 1 slab x 4 strips of 12 rows.
// Sliding-window separable 7x7 conv in registers (1-row load prefetch),
// norm written to LDS only. WDS: also emit 2x2-mean downsample of raw input.
// Writes 25 floats per (batch, block): [signal][cl, cr, sl2, sr2, sab]
template <int K, bool WDS>
__global__ __launch_bounds__(256) void fused_mscn_stats(
        const float* __restrict__ img, float* __restrict__ dsout,
        const float* __restrict__ w1d, float* __restrict__ stats,
        int H, int W) {
    constexpr int NSLAB = K / 48;
    constexpr int NSTRIP = 4 / NSLAB;
    constexpr int SROWS = K / NSTRIP;
    __shared__ float blk[K][K];
    __shared__ float red[4][25];

    const int tid = threadIdx.x;
    const int lane = tid & 63;
    const int wv = tid >> 6;
    const int slab = wv % NSLAB;
    const int strip = wv / NSLAB;
    const int bIdx = blockIdx.x;
    const int b = blockIdx.y;
    const int bh = bIdx / NB, bw = bIdx % NB;
    const int x0 = bw * K + slab * 48;
    const int gx = x0 - 3 + lane;
    const int gxc = min(max(gx, 0), W - 1);
    const int r0 = bh * K + strip * SROWS;
    const int basem3 = (lane - 3) << 2;

    const float* im = img + (size_t)b * H * W + gxc;
    const float w0=w1d[0], w1=w1d[1], w2=w1d[2], w3=w1d[3], w4=w1d[4], w5=w1d[5], w6=w1d[6];

    auto ld = [&](int r) -> float {
        int rc = min(max(r, 0), H - 1);
        return im[(size_t)rc * W];
    };
    auto hconv = [&](float v, float& omu, float& om2) {
        float a0 = bperm(basem3,      v);
        float a1 = bperm(basem3 + 4,  v);
        float a2 = bperm(basem3 + 8,  v);
        float a4 = bperm(basem3 + 16, v);
        float a5 = bperm(basem3 + 20, v);
        float a6 = bperm(basem3 + 24, v);
        omu = ((w0*a0 + w1*a1) + (w2*a2 + w3*v)) + ((w4*a4 + w5*a5) + w6*a6);
        om2 = ((w0*a0*a0 + w1*a1*a1) + (w2*a2*a2 + w3*v*v)) + ((w4*a4*a4 + w5*a5*a5) + w6*a6*a6);
    };

    float m0,m1,mm2,m3,m4,m5,m6, q0,q1,q2,q3,q4,q5,q6;
    float rA, rB, rC, dsSave = 0.f;
    float vN = ld(r0 - 3);
    { float v = vN; vN = ld(r0 - 2); hconv(v, m0,  q0); }
    { float v = vN; vN = ld(r0 - 1); hconv(v, m1,  q1); }
    { float v = vN; vN = ld(r0 + 0); hconv(v, mm2, q2); }
    { float v = vN; vN = ld(r0 + 1); hconv(v, m3,  q3); rA = v; }
    { float v = vN; vN = ld(r0 + 2); hconv(v, m4,  q4); rB = v; }
    { float v = vN; vN = ld(r0 + 3); hconv(v, m5,  q5); rC = v; }

    const bool doout = (lane >= 3) && (lane <= 50);
    const bool dsw = WDS && (lane & 1) && (lane >= 3) && (lane <= 49);

    for (int y = r0; y < r0 + SROWS; ++y) {
        float v = vN; vN = ld(y + 4);
        hconv(v, m6, q6);
        float rD = v;
        float mu = ((w0*m0 + w1*m1) + (w2*mm2 + w3*m3)) + ((w4*m4 + w5*m5) + w6*m6);
        float s2 = ((w0*q0 + w1*q1) + (w2*q2 + w3*q3)) + ((w4*q4 + w5*q5) + w6*q6);
        float sig = __builtin_amdgcn_sqrtf(fabsf(s2 - mu * mu));
        if (doout) blk[y - bh * K][slab * 48 + lane - 3] = (rA - mu) * __builtin_amdgcn_rcpf(sig + 1.0f);
        if constexpr (WDS) {
            float hs = rA + __shfl_down(rA, 1);
            if ((y & 1) == 0) dsSave = hs;
            else if (dsw)
                dsout[((size_t)b * (H / 2) + (y >> 1)) * (W / 2) + (gx >> 1)] = 0.25f * (dsSave + hs);
        }
        m0=m1; m1=mm2; mm2=m3; m3=m4; m4=m5; m5=m6;
        q0=q1; q1=q2; q2=q3; q3=q4; q4=q5; q5=q6;
        rA=rB; rB=rC; rC=rD;
    }
    __syncthreads();

    // ---- stats phase (norm tile in LDS) ----
    float acc[5][5];
    #pragma unroll
    for (int s = 0; s < 5; ++s)
        #pragma unroll
        for (int q = 0; q < 5; ++q) acc[s][q] = 0.f;

    for (int idx = tid; idx < K * K; idx += 256) {
        int i = idx / K, j = idx % K;
        int im1 = i ? i - 1 : K - 1;
        int jm1 = j ? j - 1 : K - 1;
        int jp1 = (j == K - 1) ? 0 : j + 1;
        float v0 = blk[i][j];
        float vs[5];
        vs[0] = v0;
        vs[1] = v0 * blk[i][jm1];
        vs[2] = v0 * blk[im1][j];
        vs[3] = v0 * blk[im1][jm1];
        vs[4] = v0 * blk[im1][jp1];
        #pragma unroll
        for (int s = 0; s < 5; ++s) {
            float v = vs[s];
            float v2 = v * v;
            if (v < 0.f)      { acc[s][0] += 1.f; acc[s][2] += v2; }
            else if (v > 0.f) { acc[s][1] += 1.f; acc[s][3] += v2; }
            acc[s][4] += fabsf(v);
        }
    }
    #pragma unroll
    for (int off = 32; off >= 1; off >>= 1)
        #pragma unroll
        for (int s = 0; s < 5; ++s)
            #pragma unroll
            for (int q = 0; q < 5; ++q)
                acc[s][q] += __shfl_down(acc[s][q], off);

    if (lane == 0) {
        #pragma unroll
        for (int s = 0; s < 5; ++s)
            #pragma unroll
            for (int q = 0; q < 5; ++q) red[wv][s * 5 + q] = acc[s][q];
    }
    __syncthreads();
    if (tid < 25) {
        stats[((size_t)b * NBLK + bIdx) * 25 + tid] =
            red[0][tid] + red[1][tid] + red[2][tid] + red[3][tid];
    }
}

// ---------------- AGGD closed-form + binary-search argmin ----------------
__global__ __launch_bounds__(256) void aggd_kernel(
        const float* __restrict__ stats1, const float* __restrict__ stats2,
        const float* __restrict__ rgam, const float* __restrict__ convt,
        const float* __restrict__ meanf, float* __restrict__ feats) {
    __shared__ float rg[NGRID];
    for (int i = threadIdx.x; i < NGRID; i += 256) rg[i] = rgam[i];
    __syncthreads();

    int gid = blockIdx.x * 256 + threadIdx.x;
    if (gid >= 2 * BATCH * NBLK * 5) return;
    int s = gid % 5; int t = gid / 5;
    int blk = t % NBLK; t /= NBLK;
    int b = t % BATCH; int scale = t / BATCH;

    const float* st = (scale ? stats2 : stats1) + ((size_t)b * NBLK + blk) * 25 + s * 5;
    float cl = st[0], cr = st[1], sl2 = st[2], sr2 = st[3], sab = st[4];
    float n = scale ? (48.f * 48.f) : (96.f * 96.f);

    float lstd = sqrtf(sl2 / (cl + 1e-8f));
    float rstd = sqrtf(sr2 / (cr + 1e-8f));
    float gh = lstd / rstd;
    float mab = sab / n;
    float msq = (sl2 + sr2) / n;
    float rhat = mab * mab / msq;
    float g2 = gh * gh;
    float x = rhat * (gh * g2 + 1.f) * (gh + 1.f) / ((g2 + 1.f) * (g2 + 1.f));

    // lower_bound: first index with rg[i] >= x  (rg monotone increasing)
    int lo = 0, hi = NGRID;
    while (lo < hi) {
        int mid = (lo + hi) >> 1;
        if (rg[mid] < x) lo = mid + 1; else hi = mid;
    }
    int gi;
    if (lo <= 0) gi = 0;
    else if (lo >= NGRID) gi = NGRID - 1;
    else {
        float dlo = x - rg[lo - 1];   // > 0
        float dhi = rg[lo] - x;       // >= 0
        gi = (dlo <= dhi) ? lo - 1 : lo;   // tie -> lower index (first-min)
    }

    float alpha = (float)(0.2 + 0.001 * (double)gi);
    float cv = convt[gi];
    float lb = lstd * cv, rb = rstd * cv;
    float* fo = feats + ((size_t)b * NBLK + blk) * NFEAT + (scale ? 18 : 0);
    if (s == 0) {
        fo[0] = alpha;
        fo[1] = 0.5f * (lb + rb);
    } else {
        int o = 2 + (s - 1) * 4;
        fo[o]     = alpha;
        fo[o + 1] = (rb - lb) * meanf[gi];
        fo[o + 2] = lb;
        fo[o + 3] = rb;
    }
}

// ---------------- per-batch covariance + solve + score ----------------
// cov = (cov_pris + cov_dist)/2 is SPD (lambda_min >= 0.25) -> no pivoting.
__global__ __launch_bounds__(256) void score_kernel(
        const float* __restrict__ feats, const float* __restrict__ mu_pris,
        const float* __restrict__ cov_pris, float* __restrict__ out) {
    __shared__ float F[NBLK][NFEAT];
    __shared__ double mu[NFEAT];
    __shared__ double A[NFEAT][NFEAT + 1];
    __shared__ double dff[NFEAT];
    __shared__ double fac[NFEAT];
    __shared__ double xs[NFEAT];
    int b = blockIdx.x, tid = threadIdx.x;
    const float* fp = feats + (size_t)b * NBLK * NFEAT;
    for (int i = tid; i < NBLK * NFEAT; i += 256) F[i / NFEAT][i % NFEAT] = fp[i];
    __syncthreads();
    if (tid < NFEAT) {
        double s = 0.0;
        for (int n = 0; n < NBLK; ++n) s += (double)F[n][tid];
        mu[tid] = s / (double)NBLK;
        dff[tid] = (double)mu_pris[tid] - mu[tid];
    }
    __syncthreads();
    for (int e = tid; e < NFEAT * NFEAT; e += 256) {
        int f = e / NFEAT, g = e % NFEAT;
        double mf = mu[f], mg = mu[g];
        double s = 0.0;
        for (int n = 0; n < NBLK; ++n) s += ((double)F[n][f] - mf) * ((double)F[n][g] - mg);
        A[f][g] = (s / (double)(NBLK - 1) + (double)cov_pris[f * NFEAT + g]) * 0.5;
    }
    if (tid < NFEAT) A[tid][NFEAT] = dff[tid];
    __syncthreads();
    // forward elimination, parallel rows (no pivot search)
    for (int k = 0; k < NFEAT - 1; ++k) {
        if (tid > k && tid < NFEAT) fac[tid] = A[tid][k] / A[k][k];
        __syncthreads();
        for (int e = tid; e < NFEAT * (NFEAT + 1); e += 256) {
            int r = e / (NFEAT + 1), c = e % (NFEAT + 1);
            if (r > k && c > k) A[r][c] -= fac[r] * A[k][c];
        }
        __syncthreads();
    }
    // back substitution, parallel column updates
    for (int i = NFEAT - 1; i >= 0; --i) {
        if (tid == i) xs[i] = A[i][NFEAT] / A[i][i];
        __syncthreads();
        if (tid < i) A[tid][NFEAT] -= A[tid][i] * xs[i];
        __syncthreads();
    }
    if (tid == 0) {
        double quad = 0.0;
        for (int i = 0; i < NFEAT; ++i) quad += dff[i] * xs[i];
        out[b] = (float)sqrt(fmax(quad, 0.0));
    }
}

// ---------------- launch ----------------
extern "C" void kernel_launch(void* const* d_in, const int* in_sizes, int n_in,
                              void* d_out, int out_size, void* d_ws, size_t ws_size,
                              hipStream_t stream) {
    const float* img      = (const float*)d_in[0];
    const float* mu_pris  = (const float*)d_in[1];
    const float* cov_pris = (const float*)d_in[2];
    float* out = (float*)d_out;
    float* ws = (float*)d_ws;

    const int H1 = 1056, W1 = 1056, H2 = 528, W2 = 528;
    float* rgam  = ws;                 // 9801 (pad to 9856)
    float* convt = rgam + 9856;
    float* meanf = convt + 9856;
    float* w1d   = meanf + 9856;       // 8
    float* stats1 = w1d + 8;                           // 16*121*25
    float* stats2 = stats1 + BATCH * NBLK * 25;
    float* feats  = stats2 + BATCH * NBLK * 25;        // 16*121*36
    float* dsimg  = feats + BATCH * NBLK * NFEAT;      // 16*528*528

    init_tables<<<(NGRID + 255) / 256, 256, 0, stream>>>(rgam, convt, meanf, w1d);

    fused_mscn_stats<96, true><<<dim3(NBLK, BATCH), 256, 0, stream>>>(
        img, dsimg, w1d, stats1, H1, W1);
    fused_mscn_stats<48, false><<<dim3(NBLK, BATCH), 256, 0, stream>>>(
        dsimg, nullptr, w1d, stats2, H2, W2);

    aggd_kernel<<<(2 * BATCH * NBLK * 5 + 255) / 256, 256, 0, stream>>>(
        stats1, stats2, rgam, convt, meanf, feats);

    score_kernel<<<BATCH, 256, 0, stream>>>(feats, mu_pris, cov_pris, out);
}